// Round 5
// baseline (81.135 us; speedup 1.0000x reference)
//
#include <hip/hip_runtime.h>
#include <hip/hip_bf16.h>

// Laplace attention: N=2, C=512, S=256, fp32.
// weights[n,c,d] = softmax_d( -sum_s |k[n,d,s]-q[n,c,s]| / 2 )
// out[n,c,s] = sum_d weights[n,c,d] * v[n,d,s]
//
// Round-5 structure: TC=8 q-rows per block (halves k/v L2 traffic vs TC=4),
// DSPLIT=8 d-splits -> grid = 2*64*8 = 1024 blocks, 256 threads.
// Flash-style unnormalized partials (o, m, l) in workspace; combine kernel.
// Phase 2: 2 k-rows per pass (32 lanes each, lane owns s-octet), DPP reduce,
// lanes 31/63 write logits directly to LDS (no readlane round-trip).

constexpr int N_ = 2;
constexpr int C_ = 512;
constexpr int S_ = 256;
constexpr int TC = 8;             // q-rows per block
constexpr int NW = 4;             // waves per block
constexpr int DSPLIT = 8;
constexpr int DH  = C_ / DSPLIT;  // 64 d-rows per block
constexpr int DPW = DH / NW;      // 16 d-rows per wave

constexpr size_t PO_SZ = (size_t)N_ * C_ * DSPLIT * S_;  // partial o
constexpr size_t ST_SZ = (size_t)N_ * C_ * DSPLIT;       // partial m/l

// DPP helpers: ctrl/row_mask are template params (must be constants).
template <int CTRL, int ROW_MASK>
__device__ __forceinline__ float dpp_add(float x) {
    int yi = __builtin_amdgcn_update_dpp(0, __float_as_int(x), CTRL, ROW_MASK, 0xf, true);
    return x + __int_as_float(yi);
}
template <int CTRL, int ROW_MASK>
__device__ __forceinline__ float dpp_max(float x) {
    int yi = __builtin_amdgcn_update_dpp(__float_as_int(x), __float_as_int(x), CTRL, ROW_MASK, 0xf, false);
    return fmaxf(x, __int_as_float(yi));
}
// After this: lane31 = sum(lanes 0..31), lane63 = sum(lanes 32..63).
__device__ __forceinline__ float dpp_reduce_halves(float x) {
    x = dpp_add<0x111, 0xf>(x);   // row_shr:1
    x = dpp_add<0x112, 0xf>(x);   // row_shr:2
    x = dpp_add<0x114, 0xf>(x);   // row_shr:4
    x = dpp_add<0x118, 0xf>(x);   // row_shr:8
    x = dpp_add<0x142, 0xa>(x);   // row_bcast15 into rows 1,3
    return x;
}
__device__ __forceinline__ float wave_sum_bcast(float x) {
    x = dpp_reduce_halves(x);
    x = dpp_add<0x143, 0xc>(x);   // row_bcast31 -> lane63 = total
    return __int_as_float(__builtin_amdgcn_readlane(__float_as_int(x), 63));
}
__device__ __forceinline__ float wave_max_bcast(float x) {
    x = dpp_max<0x111, 0xf>(x);
    x = dpp_max<0x112, 0xf>(x);
    x = dpp_max<0x114, 0xf>(x);
    x = dpp_max<0x118, 0xf>(x);
    x = dpp_max<0x142, 0xa>(x);
    x = dpp_max<0x143, 0xc>(x);
    return __int_as_float(__builtin_amdgcn_readlane(__float_as_int(x), 63));
}

__global__ __launch_bounds__(256, 4)
void laplace_attn_main(const float* __restrict__ q,
                       const float* __restrict__ k,
                       const float* __restrict__ v,
                       float* __restrict__ ws) {
    constexpr int per_n = (C_ / TC) * DSPLIT;   // 512
    const int b    = blockIdx.x;                // 0..1023
    const int n    = b / per_n;
    const int r    = b - n * per_n;
    const int half = r % DSPLIT;
    const int c0   = (r / DSPLIT) * TC;
    const int tid  = threadIdx.x;
    const int w    = tid >> 6;
    const int lane = tid & 63;

    const float* kbase = k + (size_t)n * C_ * S_;
    const float* vbase = v + (size_t)n * C_ * S_;

    float* po = ws;                   // [N*C][DSPLIT][S]
    float* pm = ws + PO_SZ;           // [N*C][DSPLIT]
    float* pl = pm + ST_SZ;           // [N*C][DSPLIT]

    __shared__ float4 wt[DH][2];              // per d: 8 logits->exp (2 KB)
    __shared__ float4 accs[NW][TC][64];       // per-wave o partials (32 KB)

    // ---- q octets in registers: lane serves row-half h, s-octet j ----
    const int h = lane >> 5;
    const int j = lane & 31;
    float4 qa[TC], qb[TC];
    #pragma unroll
    for (int c = 0; c < TC; ++c) {
        const float4* qr = (const float4*)(q + ((size_t)n * C_ + c0 + c) * S_);
        qa[c] = qr[2 * j];
        qb[c] = qr[2 * j + 1];
    }

    const int dw0 = half * DH + w * DPW;      // first global d-row for this wave
    const float* kw = kbase + (size_t)dw0 * S_;

    // ---- phase 2: logits, 2 k-rows per pass ----
    #pragma unroll 2
    for (int g2 = 0; g2 < DPW; g2 += 2) {
        const float4* rp = (const float4*)(kw + (size_t)(g2 + h) * S_ + j * 8);
        const float4 ka = rp[0];
        const float4 kb = rp[1];
        float vals[TC];
        #pragma unroll
        for (int c = 0; c < TC; ++c) {
            float p = fabsf(ka.x - qa[c].x) + fabsf(ka.y - qa[c].y)
                    + fabsf(ka.z - qa[c].z) + fabsf(ka.w - qa[c].w)
                    + fabsf(kb.x - qb[c].x) + fabsf(kb.y - qb[c].y)
                    + fabsf(kb.z - qb[c].z) + fabsf(kb.w - qb[c].w);
            vals[c] = dpp_reduce_halves(p);   // lane31/63 hold the 2 row sums
        }
        if ((lane & 31) == 31) {              // lanes 31 and 63 write their row
            const int row = w * DPW + g2 + h;
            wt[row][0] = make_float4(-0.5f * vals[0], -0.5f * vals[1],
                                     -0.5f * vals[2], -0.5f * vals[3]);
            wt[row][1] = make_float4(-0.5f * vals[4], -0.5f * vals[5],
                                     -0.5f * vals[6], -0.5f * vals[7]);
        }
    }
    __syncthreads();

    // ---- softmax (partial, unnormalized): wave w handles c = 2w, 2w+1 ----
    {
        float* wtf = (float*)wt;              // [DH][8]
        #pragma unroll
        for (int cc = 0; cc < 2; ++cc) {
            const int c = 2 * w + cc;
            const float x = wtf[lane * 8 + c];    // one logit per lane (DH=64)
            const float m = wave_max_bcast(x);
            const float e = __expf(x - m);
            const float l = wave_sum_bcast(e);
            wtf[lane * 8 + c] = e;
            if (lane == 0) {
                const size_t sidx = ((size_t)n * C_ + c0 + c) * DSPLIT + half;
                pm[sidx] = m;
                pl[sidx] = l;
            }
        }
    }
    __syncthreads();

    // ---- phase 4: o_partial[c] = sum_d e[c][d] * v[d,:] (lane owns s-quad) ----
    float4 acc[TC];
    #pragma unroll
    for (int c = 0; c < TC; ++c) acc[c] = make_float4(0.f, 0.f, 0.f, 0.f);

    const float4* v4 = (const float4*)(vbase + (size_t)dw0 * S_);
    #pragma unroll 4
    for (int dd = 0; dd < DPW; ++dd) {
        const float4 vv = v4[dd * 64 + lane];
        const float4 w0 = wt[w * DPW + dd][0];   // uniform broadcast reads
        const float4 w1 = wt[w * DPW + dd][1];
        acc[0].x += w0.x * vv.x; acc[0].y += w0.x * vv.y;
        acc[0].z += w0.x * vv.z; acc[0].w += w0.x * vv.w;
        acc[1].x += w0.y * vv.x; acc[1].y += w0.y * vv.y;
        acc[1].z += w0.y * vv.z; acc[1].w += w0.y * vv.w;
        acc[2].x += w0.z * vv.x; acc[2].y += w0.z * vv.y;
        acc[2].z += w0.z * vv.z; acc[2].w += w0.z * vv.w;
        acc[3].x += w0.w * vv.x; acc[3].y += w0.w * vv.y;
        acc[3].z += w0.w * vv.z; acc[3].w += w0.w * vv.w;
        acc[4].x += w1.x * vv.x; acc[4].y += w1.x * vv.y;
        acc[4].z += w1.x * vv.z; acc[4].w += w1.x * vv.w;
        acc[5].x += w1.y * vv.x; acc[5].y += w1.y * vv.y;
        acc[5].z += w1.y * vv.z; acc[5].w += w1.y * vv.w;
        acc[6].x += w1.z * vv.x; acc[6].y += w1.z * vv.y;
        acc[6].z += w1.z * vv.z; acc[6].w += w1.z * vv.w;
        acc[7].x += w1.w * vv.x; acc[7].y += w1.w * vv.y;
        acc[7].z += w1.w * vv.z; acc[7].w += w1.w * vv.w;
    }
    #pragma unroll
    for (int c = 0; c < TC; ++c) accs[w][c][lane] = acc[c];
    __syncthreads();

    // ---- epilogue: combine the 4 waves' partials, write workspace ----
    #pragma unroll
    for (int cc = 0; cc < 2; ++cc) {
        const int c = w + NW * cc;            // waves cover c = 0..7
        const float4 a0 = accs[0][c][lane];
        const float4 a1 = accs[1][c][lane];
        const float4 a2 = accs[2][c][lane];
        const float4 a3 = accs[3][c][lane];
        float4 o;
        o.x = (a0.x + a1.x) + (a2.x + a3.x);
        o.y = (a0.y + a1.y) + (a2.y + a3.y);
        o.z = (a0.z + a1.z) + (a2.z + a3.z);
        o.w = (a0.w + a1.w) + (a2.w + a3.w);
        const size_t oidx = (((size_t)n * C_ + c0 + c) * DSPLIT + half) * S_;
        ((float4*)(po + oidx))[lane] = o;
    }
}

__global__ __launch_bounds__(64)
void laplace_attn_combine(const float* __restrict__ ws,
                          float* __restrict__ out) {
    const int b    = blockIdx.x;      // (n*C + c), 0..1023
    const int lane = threadIdx.x;     // s-quad

    const float* po = ws;
    const float* pm = ws + PO_SZ;
    const float* pl = pm + ST_SZ;

    float m[DSPLIT], l[DSPLIT];
    #pragma unroll
    for (int hh = 0; hh < DSPLIT; ++hh) {
        m[hh] = pm[(size_t)b * DSPLIT + hh];
        l[hh] = pl[(size_t)b * DSPLIT + hh];
    }
    float M = m[0];
    #pragma unroll
    for (int hh = 1; hh < DSPLIT; ++hh) M = fmaxf(M, m[hh]);
    float den = 0.f, a[DSPLIT];
    #pragma unroll
    for (int hh = 0; hh < DSPLIT; ++hh) { a[hh] = __expf(m[hh] - M); den += a[hh] * l[hh]; }
    const float inv = 1.f / den;

    float4 rsum = make_float4(0.f, 0.f, 0.f, 0.f);
    #pragma unroll
    for (int hh = 0; hh < DSPLIT; ++hh) {
        const float4 o = ((const float4*)(po + ((size_t)b * DSPLIT + hh) * S_))[lane];
        rsum.x += a[hh] * o.x;
        rsum.y += a[hh] * o.y;
        rsum.z += a[hh] * o.z;
        rsum.w += a[hh] * o.w;
    }
    float4 rr;
    rr.x = rsum.x * inv; rr.y = rsum.y * inv;
    rr.z = rsum.z * inv; rr.w = rsum.w * inv;
    ((float4*)(out + (size_t)b * S_))[lane] = rr;
}

extern "C" void kernel_launch(void* const* d_in, const int* in_sizes, int n_in,
                              void* d_out, int out_size, void* d_ws, size_t ws_size,
                              hipStream_t stream) {
    const float* q = (const float*)d_in[0];
    const float* k = (const float*)d_in[1];
    const float* v = (const float*)d_in[2];
    float* out = (float*)d_out;
    float* ws  = (float*)d_ws;

    laplace_attn_main<<<dim3(N_ * (C_ / TC) * DSPLIT), dim3(256), 0, stream>>>(q, k, v, ws);
    laplace_attn_combine<<<dim3(N_ * C_), dim3(64), 0, stream>>>(ws, out);
}